// Round 1
// baseline (151.772 us; speedup 1.0000x reference)
//
#include <hip/hip_runtime.h>

#define NBATCH 32
#define LPATH 256
#define NC 8
#define SIGLEN 4680   // 8 + 64 + 512 + 4096

// One block per batch element; 256 threads.
// Thread t owns:
//   level-4 elements idx4 = 16t .. 16t+15   (registers, 16 floats)
//   level-3 elements idx3 = 2t, 2t+1        (registers; exactly the S3 values
//                                            its level-4 update reads)
//   level-2 element  t (if t<64)            (register + LDS mirror)
//   level-1 element  t (if t<8)             (register + LDS mirror)
// Decomposition of idx4 = ((a*8+b)*8+c)*8+e :
//   a = t>>5, b = (t>>2)&7, c = c0 + (j>>3) with c0 = (t&3)*2, e = j&7
// idx3 = 2t+cc corresponds to (a, b, c0+cc) — same a,b,c as level 4. 
__global__ __launch_bounds__(256) void sig_scan_kernel(
    const float* __restrict__ path, float* __restrict__ out) {
    const int n = blockIdx.x;
    const int t = threadIdx.x;

    __shared__ float pbuf[LPATH * NC];   // 8 KB path row
    __shared__ float sh_S1[NC];
    __shared__ float sh_S2[NC * NC];

    // stage path row (coalesced)
    const float* prow = path + n * (LPATH * NC);
    #pragma unroll
    for (int i = t; i < LPATH * NC; i += 256) pbuf[i] = prow[i];

    const int a  = t >> 5;
    const int b  = (t >> 2) & 7;
    const int c0 = (t & 3) * 2;

    float S4[16];
    #pragma unroll
    for (int j = 0; j < 16; ++j) S4[j] = 0.f;
    float S3r0 = 0.f, S3r1 = 0.f;
    float S2r = 0.f;
    float S1r = 0.f;
    if (t < NC) sh_S1[t] = 0.f;
    if (t < NC * NC) sh_S2[t] = 0.f;
    __syncthreads();

    const float inv24 = 1.f / 24.f;
    const float inv6  = 1.f / 6.f;

    for (int s = 0; s < LPATH - 1; ++s) {
        // segment increment (broadcast LDS reads, conflict-free)
        float d[NC];
        #pragma unroll
        for (int c = 0; c < NC; ++c)
            d[c] = pbuf[(s + 1) * NC + c] - pbuf[s * NC + c];

        // ---- read OLD shared state ----
        const float oS1   = sh_S1[a];
        const float oS2   = sh_S2[a * 8 + b];
        const float oS1_2 = (t < 64) ? sh_S1[t >> 3] : 0.f;
        __syncthreads();   // all reads of old S1/S2 complete

        // ---- level 4: S4[abce] += d[e] * (d[c]*P + oldS3[abc]) ----
        const float dab = d[a] * d[b];
        const float P = dab * inv24 + oS1 * (d[b] * inv6) + oS2 * 0.5f;
        {
            const float K0 = d[c0] * P + S3r0;
            #pragma unroll
            for (int e = 0; e < 8; ++e) S4[e] += d[e] * K0;
            const float K1 = d[c0 + 1] * P + S3r1;
            #pragma unroll
            for (int e = 0; e < 8; ++e) S4[8 + e] += d[e] * K1;
        }

        // ---- level 3: S3[abc] += d[c] * Q ----
        const float Q = dab * inv6 + oS1 * (d[b] * 0.5f) + oS2;
        S3r0 += d[c0] * Q;
        S3r1 += d[c0 + 1] * Q;

        // ---- level 2 (t<64): S2[a2,b2] += d[b2]*(d[a2]/2 + oldS1[a2]) ----
        if (t < 64) {
            const int a2 = t >> 3, b2 = t & 7;
            S2r += d[b2] * (d[a2] * 0.5f + oS1_2);
        }
        // ---- level 1 (t<8) ----
        if (t < 8) S1r += d[t];

        // publish new S1/S2 for next iteration
        if (t < 64) sh_S2[t] = S2r;
        if (t < 8)  sh_S1[t] = S1r;
        __syncthreads();
    }

    // ---- write output: [S1(8) | S2(64) | S3(512) | S4(4096)] per batch ----
    float* o = out + n * SIGLEN;
    if (t < 8)  o[t] = S1r;
    if (t < 64) o[8 + t] = S2r;
    o[72 + 2 * t]     = S3r0;
    o[72 + 2 * t + 1] = S3r1;
    #pragma unroll
    for (int j = 0; j < 16; ++j) o[584 + 16 * t + j] = S4[j];
}

extern "C" void kernel_launch(void* const* d_in, const int* in_sizes, int n_in,
                              void* d_out, int out_size, void* d_ws, size_t ws_size,
                              hipStream_t stream) {
    const float* path = (const float*)d_in[0];
    float* out = (float*)d_out;
    sig_scan_kernel<<<NBATCH, 256, 0, stream>>>(path, out);
}

// Round 2
// 20.817 us; speedup vs baseline: 7.2909x; 7.2909x over previous
//
#include <hip/hip_runtime.h>

#define NBATCH 32
#define LPATH 256
#define NSEG 255          // L-1 segments
#define SIGLEN 4680       // 8 + 64 + 512 + 4096
#define INV6 (1.0f/6.0f)
#define INV24 (1.0f/24.0f)

// Combine buffer: one wave's full signature, in exchange-friendly layouts.
//  T4t : level-4 transposed [ (c*8+e)*64 + lane ]  -> conflict-free r/w
//  T3b : level-3 rows by FIRST tensor index, padded stride 68:
//        [ x*68 + y*8 + z ]  (x,y,z = tensor indices)
//        writes: lane(a,b) -> x=a,y=b,z=c  (2-way max, free)
//        R4 read: x=b_lane, y=c, z=e as float4 pairs (banks 4b+8c, conflict-free)
//        R3 read: x=a, y=b, z=c scalar      (2-way, free)
//  T2  : [ a*8+b ]    T1 : [ a ]
struct __align__(16) CBuf {
    float T4t[64 * 64];   // 16384 B
    float T3b[8 * 68];    //  2176 B
    float T2[64];         //   256 B
    float T1[8];          //    32 B
};

// One block per batch element. 8 waves; wave w scans segments [32w, min(32w+32,255)),
// keeping its whole truncated signature in registers:
//   lane l = (a<<3)|b owns S2[a,b], S3[a,b,c] (8), S4[a,b,c,e] (64); a1a = S1[a].
// Per step (Chen with rank-1 exp(d)):
//   P = d_a d_b/24 + S1[a] d_b/6 + S2/2 ;  Q = d_a d_b/6 + S1[a] d_b/2 + S2
//   S4[ce] += d_e*(d_c*P + S3[c]) ; S3[c] += d_c*Q ; S2 += d_b*(d_a/2+S1[a]) ; S1[a]+=d_a
// Then 3 tree rounds of the general Chen product (left wave absorbs right's LDS copy).
__global__ __launch_bounds__(512) void sig_kernel(const float* __restrict__ path,
                                                  float* __restrict__ out) {
    const int n = blockIdx.x;
    const int t = threadIdx.x;
    const int w = t >> 6;    // wave id 0..7
    const int l = t & 63;    // lane
    const int a = l >> 3;
    const int b = l & 7;

    __shared__ float dbuf[NSEG * 8];   // 8160 B of increments
    __shared__ CBuf bufs[4];           // 75392 B

    // increments, coalesced from global
    const float* prow = path + n * (LPATH * 8);
    for (int i = t; i < NSEG * 8; i += 512) dbuf[i] = prow[i + 8] - prow[i];
    __syncthreads();

    // ---- register state ----
    float S4[64];
    float S3[8];
    #pragma unroll
    for (int j = 0; j < 64; ++j) S4[j] = 0.f;
    #pragma unroll
    for (int c = 0; c < 8; ++c) S3[c] = 0.f;
    float S2 = 0.f, a1a = 0.f;

    // ---- chunk scan: 32 (or 31) rank-1 steps, no barriers ----
    const int s0 = w * 32;
    const int s1 = (s0 + 32 < NSEG) ? (s0 + 32) : NSEG;
    for (int s = s0; s < s1; ++s) {
        const float4 dlo = *(const float4*)&dbuf[s * 8];
        const float4 dhi = *(const float4*)&dbuf[s * 8 + 4];
        const float dr[8] = {dlo.x, dlo.y, dlo.z, dlo.w, dhi.x, dhi.y, dhi.z, dhi.w};
        const float da = dbuf[s * 8 + a];   // 8 distinct addrs, 8 banks: free
        const float db = dbuf[s * 8 + b];
        const float dab = da * db;
        const float P = dab * INV24 + a1a * db * INV6 + S2 * 0.5f;
        const float Q = dab * INV6  + a1a * db * 0.5f + S2;
        float K[8];
        #pragma unroll
        for (int c = 0; c < 8; ++c) K[c] = dr[c] * P + S3[c];
        #pragma unroll
        for (int c = 0; c < 8; ++c)
            #pragma unroll
            for (int e = 0; e < 8; ++e)
                S4[c * 8 + e] += dr[e] * K[c];
        #pragma unroll
        for (int c = 0; c < 8; ++c) S3[c] += dr[c] * Q;
        S2 += db * (da * 0.5f + a1a);
        a1a += da;
    }

    // ---- tree combine: rounds stride = 1, 2, 4 ----
    #pragma unroll
    for (int r = 0; r < 3; ++r) {
        const int stride = 1 << r;
        const int m = (stride << 1) - 1;

        if ((w & m) == stride) {           // right wave: publish
            CBuf& B = bufs[w >> (r + 1)];
            #pragma unroll
            for (int c = 0; c < 8; ++c)
                #pragma unroll
                for (int e = 0; e < 8; ++e)
                    B.T4t[(c * 8 + e) * 64 + l] = S4[c * 8 + e];
            #pragma unroll
            for (int c = 0; c < 8; ++c)
                B.T3b[a * 68 + b * 8 + c] = S3[c];
            B.T2[l] = S2;
            if (b == 0) B.T1[a] = a1a;
        }
        __syncthreads();

        if ((w & m) == 0) {                // left wave: absorb  R = A (.) T
            const CBuf& B = bufs[w >> (r + 1)];
            const float4 t1lo = *(const float4*)&B.T1[0];
            const float4 t1hi = *(const float4*)&B.T1[4];
            const float t1r[8] = {t1lo.x, t1lo.y, t1lo.z, t1lo.w,
                                  t1hi.x, t1hi.y, t1hi.z, t1hi.w};
            const float t1a = B.T1[a];
            const float t1b = B.T1[b];
            // R4[abce] = A4 + A3[abc] T1[e] + A2[ab] T2[ce] + A1[a] T3[bce] + T4
            #pragma unroll
            for (int c = 0; c < 8; ++c) {
                const float4 t2lo = *(const float4*)&B.T2[c * 8];
                const float4 t2hi = *(const float4*)&B.T2[c * 8 + 4];
                const float t2r[8] = {t2lo.x, t2lo.y, t2lo.z, t2lo.w,
                                      t2hi.x, t2hi.y, t2hi.z, t2hi.w};
                const float4 t3lo = *(const float4*)&B.T3b[b * 68 + c * 8];
                const float4 t3hi = *(const float4*)&B.T3b[b * 68 + c * 8 + 4];
                const float t3r[8] = {t3lo.x, t3lo.y, t3lo.z, t3lo.w,
                                      t3hi.x, t3hi.y, t3hi.z, t3hi.w};
                #pragma unroll
                for (int e = 0; e < 8; ++e)
                    S4[c * 8 + e] += S3[c] * t1r[e] + S2 * t2r[e]
                                   + a1a * t3r[e] + B.T4t[(c * 8 + e) * 64 + l];
            }
            // R3[abc] = A3 + A2[ab] T1[c] + A1[a] T2[bc] + T3[abc]
            #pragma unroll
            for (int c = 0; c < 8; ++c)
                S3[c] += S2 * t1r[c] + a1a * B.T2[b * 8 + c]
                       + B.T3b[a * 68 + b * 8 + c];
            // R2[ab] = A2 + A1[a] T1[b] + T2[ab]
            S2 += a1a * t1b + B.T2[l];
            // R1
            a1a += t1a;
        }
        __syncthreads();
    }

    // ---- wave 0 holds the full signature: write out ----
    if (w == 0) {
        float* o = out + n * SIGLEN;
        if (b == 0) o[a] = a1a;
        o[8 + l] = S2;
        *(float4*)&o[72 + l * 8]     = make_float4(S3[0], S3[1], S3[2], S3[3]);
        *(float4*)&o[72 + l * 8 + 4] = make_float4(S3[4], S3[5], S3[6], S3[7]);
        #pragma unroll
        for (int q = 0; q < 16; ++q)
            *(float4*)&o[584 + l * 64 + q * 4] =
                make_float4(S4[q * 4], S4[q * 4 + 1], S4[q * 4 + 2], S4[q * 4 + 3]);
    }
}

extern "C" void kernel_launch(void* const* d_in, const int* in_sizes, int n_in,
                              void* d_out, int out_size, void* d_ws, size_t ws_size,
                              hipStream_t stream) {
    const float* path = (const float*)d_in[0];
    float* out = (float*)d_out;
    sig_kernel<<<NBATCH, 512, 0, stream>>>(path, out);
}